// Round 1
// baseline (1067.245 us; speedup 1.0000x reference)
//
#include <hip/hip_runtime.h>
#include <hip/hip_bf16.h>

// Fixed problem shape from reference: B=2, S=2048, E=1024, H=16, Dh=64, fp32.
#define S_LEN 2048
#define E_DIM 1024
#define NHEAD 16
#define DHEAD 64
#define BATCH 2

// ---------------------------------------------------------------------------
// QKV projection: y = x @ W^T + b for W in {Wq,Wk,Wv}, written as [B,H,S,Dh].
// 128x128 tile, BK=16, 8x8 micro-tile/thread, float4 LDS reads.
// grid = (M/128, E/128, 3), block = 256.
// ---------------------------------------------------------------------------
__global__ __launch_bounds__(256) void qkv_gemm_kernel(
    const float* __restrict__ x,
    const float* __restrict__ Wq, const float* __restrict__ bq,
    const float* __restrict__ Wk, const float* __restrict__ bk,
    const float* __restrict__ Wv, const float* __restrict__ bv,
    float* __restrict__ qo, float* __restrict__ ko, float* __restrict__ vo)
{
    const int which = blockIdx.z;
    const float* __restrict__ W    = (which == 0) ? Wq : (which == 1) ? Wk : Wv;
    const float* __restrict__ bias = (which == 0) ? bq : (which == 1) ? bk : bv;
    float* __restrict__ out        = (which == 0) ? qo : (which == 1) ? ko : vo;

    const int m0 = blockIdx.x * 128;
    const int n0 = blockIdx.y * 128;
    const int tid = threadIdx.x;

    // k-major staging; stride 132 floats = 528 B (16B-aligned rows, bank-friendly)
    __shared__ float As[16][132];  // [k][m]
    __shared__ float Bs[16][132];  // [k][n]

    float acc[8][8];
    #pragma unroll
    for (int i = 0; i < 8; ++i)
        #pragma unroll
        for (int j = 0; j < 8; ++j) acc[i][j] = 0.f;

    const int ty = tid >> 4;        // 0..15 -> m sub-block
    const int tx = tid & 15;        // 0..15 -> n sub-block
    const int lrow = tid >> 2;      // 0..63
    const int lc4  = (tid & 3) * 4; // 0,4,8,12

    for (int k0 = 0; k0 < E_DIM; k0 += 16) {
        #pragma unroll
        for (int half = 0; half < 2; ++half) {
            const int row = lrow + half * 64;
            const float4 xa = *reinterpret_cast<const float4*>(
                &x[(size_t)(m0 + row) * E_DIM + k0 + lc4]);
            const float4 wa = *reinterpret_cast<const float4*>(
                &W[(size_t)(n0 + row) * E_DIM + k0 + lc4]);
            As[lc4 + 0][row] = xa.x; As[lc4 + 1][row] = xa.y;
            As[lc4 + 2][row] = xa.z; As[lc4 + 3][row] = xa.w;
            Bs[lc4 + 0][row] = wa.x; Bs[lc4 + 1][row] = wa.y;
            Bs[lc4 + 2][row] = wa.z; Bs[lc4 + 3][row] = wa.w;
        }
        __syncthreads();
        #pragma unroll
        for (int kk = 0; kk < 16; ++kk) {
            const float4 a0 = *reinterpret_cast<const float4*>(&As[kk][ty * 8]);
            const float4 a1 = *reinterpret_cast<const float4*>(&As[kk][ty * 8 + 4]);
            const float4 b0 = *reinterpret_cast<const float4*>(&Bs[kk][tx * 8]);
            const float4 b1 = *reinterpret_cast<const float4*>(&Bs[kk][tx * 8 + 4]);
            const float a[8] = {a0.x, a0.y, a0.z, a0.w, a1.x, a1.y, a1.z, a1.w};
            const float b[8] = {b0.x, b0.y, b0.z, b0.w, b1.x, b1.y, b1.z, b1.w};
            #pragma unroll
            for (int i = 0; i < 8; ++i)
                #pragma unroll
                for (int j = 0; j < 8; ++j)
                    acc[i][j] = fmaf(a[i], b[j], acc[i][j]);
        }
        __syncthreads();
    }

    // epilogue: bias + permuted store to [B,H,S,Dh]
    const int n = n0 + tx * 8;
    float bb[8];
    #pragma unroll
    for (int j = 0; j < 8; ++j) bb[j] = bias[n + j];
    const int h = n >> 6;      // 8 | 64, so all 8 cols share one head
    const int d = n & 63;
    #pragma unroll
    for (int i = 0; i < 8; ++i) {
        const int m = m0 + ty * 8 + i;
        const int b = m >> 11;            // m / S_LEN
        const int s = m & (S_LEN - 1);
        float* op = &out[(((size_t)(b * NHEAD + h)) * S_LEN + s) * DHEAD + d];
        float4 r0, r1;
        r0.x = acc[i][0] + bb[0]; r0.y = acc[i][1] + bb[1];
        r0.z = acc[i][2] + bb[2]; r0.w = acc[i][3] + bb[3];
        r1.x = acc[i][4] + bb[4]; r1.y = acc[i][5] + bb[5];
        r1.z = acc[i][6] + bb[6]; r1.w = acc[i][7] + bb[7];
        *reinterpret_cast<float4*>(op)     = r0;
        *reinterpret_cast<float4*>(op + 4) = r1;
    }
}

// ---------------------------------------------------------------------------
// Flash-style attention, fp32. Per block: one (b,h), 64 query rows.
// Iterate 64-row K/V tiles (shared LDS buffer), online softmax.
// grid = (B*H, S/64), block = 256 (16x16 threads, 4x4 micro-tiles).
// ---------------------------------------------------------------------------
__global__ __launch_bounds__(256) void attn_kernel(
    const float* __restrict__ q, const float* __restrict__ k,
    const float* __restrict__ v, float* __restrict__ out)
{
    const int bh = blockIdx.x;           // 0..B*H-1
    const int q0 = blockIdx.y * 64;
    const int b  = bh >> 4;              // bh / NHEAD
    const int h  = bh & 15;
    const float* __restrict__ Q = q + (size_t)bh * S_LEN * DHEAD;
    const float* __restrict__ K = k + (size_t)bh * S_LEN * DHEAD;
    const float* __restrict__ V = v + (size_t)bh * S_LEN * DHEAD;

    __shared__ float Qs[64][65];
    __shared__ float KVs[64][65];
    __shared__ float Ps[64][65];

    const int tid = threadIdx.x;
    const int ty = tid >> 4;   // q-row group (4 rows)
    const int tx = tid & 15;   // k-col / d-col group (4 cols)

    // load Q tile (64x64), coalesced 16B/lane
    #pragma unroll
    for (int it = 0; it < 4; ++it) {
        const int f = tid + it * 256;       // 0..1023 float4s
        const int row = f >> 4, c4 = (f & 15) * 4;
        const float4 a = *reinterpret_cast<const float4*>(
            &Q[(size_t)(q0 + row) * DHEAD + c4]);
        Qs[row][c4 + 0] = a.x; Qs[row][c4 + 1] = a.y;
        Qs[row][c4 + 2] = a.z; Qs[row][c4 + 3] = a.w;
    }

    float m_run[4], l_run[4], alpha[4], o[4][4];
    #pragma unroll
    for (int i = 0; i < 4; ++i) {
        m_run[i] = -1e30f; l_run[i] = 0.f;
        #pragma unroll
        for (int j = 0; j < 4; ++j) o[i][j] = 0.f;
    }
    __syncthreads();

    for (int t0 = 0; t0 < S_LEN; t0 += 64) {
        // ---- load K tile ----
        #pragma unroll
        for (int it = 0; it < 4; ++it) {
            const int f = tid + it * 256;
            const int row = f >> 4, c4 = (f & 15) * 4;
            const float4 a = *reinterpret_cast<const float4*>(
                &K[(size_t)(t0 + row) * DHEAD + c4]);
            KVs[row][c4 + 0] = a.x; KVs[row][c4 + 1] = a.y;
            KVs[row][c4 + 2] = a.z; KVs[row][c4 + 3] = a.w;
        }
        __syncthreads();

        // ---- scores: S = (Q K^T) * 1/sqrt(Dh) ----
        float s[4][4];
        #pragma unroll
        for (int i = 0; i < 4; ++i)
            #pragma unroll
            for (int j = 0; j < 4; ++j) s[i][j] = 0.f;

        for (int dd = 0; dd < DHEAD; ++dd) {
            float a[4], bcol[4];
            #pragma unroll
            for (int i = 0; i < 4; ++i) a[i] = Qs[ty * 4 + i][dd];
            #pragma unroll
            for (int j = 0; j < 4; ++j) bcol[j] = KVs[tx * 4 + j][dd];
            #pragma unroll
            for (int i = 0; i < 4; ++i)
                #pragma unroll
                for (int j = 0; j < 4; ++j)
                    s[i][j] = fmaf(a[i], bcol[j], s[i][j]);
        }

        // ---- online softmax update (row groups of 16 lanes share a q-row) ----
        #pragma unroll
        for (int i = 0; i < 4; ++i) {
            float mt = fmaxf(fmaxf(s[i][0], s[i][1]), fmaxf(s[i][2], s[i][3])) * 0.125f;
            #pragma unroll
            for (int off = 1; off < 16; off <<= 1)
                mt = fmaxf(mt, __shfl_xor(mt, off));
            const float mn = fmaxf(m_run[i], mt);
            float p[4], lt = 0.f;
            #pragma unroll
            for (int j = 0; j < 4; ++j) {
                p[j] = __expf(s[i][j] * 0.125f - mn);
                lt += p[j];
            }
            #pragma unroll
            for (int off = 1; off < 16; off <<= 1)
                lt += __shfl_xor(lt, off);
            alpha[i] = __expf(m_run[i] - mn);
            l_run[i] = l_run[i] * alpha[i] + lt;
            m_run[i] = mn;
            #pragma unroll
            for (int j = 0; j < 4; ++j)
                Ps[ty * 4 + i][tx * 4 + j] = p[j];
        }
        __syncthreads();   // scores done reading KVs; Ps fully written

        // ---- load V tile into the shared K/V buffer ----
        #pragma unroll
        for (int it = 0; it < 4; ++it) {
            const int f = tid + it * 256;
            const int row = f >> 4, c4 = (f & 15) * 4;
            const float4 a = *reinterpret_cast<const float4*>(
                &V[(size_t)(t0 + row) * DHEAD + c4]);
            KVs[row][c4 + 0] = a.x; KVs[row][c4 + 1] = a.y;
            KVs[row][c4 + 2] = a.z; KVs[row][c4 + 3] = a.w;
        }
        __syncthreads();

        // ---- PV accumulate with per-row rescale ----
        #pragma unroll
        for (int i = 0; i < 4; ++i)
            #pragma unroll
            for (int j = 0; j < 4; ++j) o[i][j] *= alpha[i];

        for (int kk = 0; kk < 64; ++kk) {
            float a[4], bcol[4];
            #pragma unroll
            for (int i = 0; i < 4; ++i) a[i] = Ps[ty * 4 + i][kk];
            #pragma unroll
            for (int j = 0; j < 4; ++j) bcol[j] = KVs[kk][tx * 4 + j];
            #pragma unroll
            for (int i = 0; i < 4; ++i)
                #pragma unroll
                for (int j = 0; j < 4; ++j)
                    o[i][j] = fmaf(a[i], bcol[j], o[i][j]);
        }
        __syncthreads();   // PV done reading KVs/Ps before next tile overwrites
    }

    // ---- normalize + write out[B,S,H*Dh] ----
    #pragma unroll
    for (int i = 0; i < 4; ++i) {
        const int qr = q0 + ty * 4 + i;
        const float inv = 1.f / l_run[i];
        float* op = &out[((size_t)(b * S_LEN + qr)) * E_DIM + h * DHEAD + tx * 4];
        float4 r;
        r.x = o[i][0] * inv; r.y = o[i][1] * inv;
        r.z = o[i][2] * inv; r.w = o[i][3] * inv;
        *reinterpret_cast<float4*>(op) = r;
    }
}

// ---------------------------------------------------------------------------
extern "C" void kernel_launch(void* const* d_in, const int* in_sizes, int n_in,
                              void* d_out, int out_size, void* d_ws, size_t ws_size,
                              hipStream_t stream) {
    const float* x  = (const float*)d_in[0];
    const float* Wq = (const float*)d_in[1];
    const float* bq = (const float*)d_in[2];
    const float* Wk = (const float*)d_in[3];
    const float* bk = (const float*)d_in[4];
    const float* Wv = (const float*)d_in[5];
    const float* bv = (const float*)d_in[6];
    float* out = (float*)d_out;

    // workspace: Q,K,V in [B,H,S,Dh] fp32 -> 3 * 16 MB = 48 MB
    const size_t qkv_elems = (size_t)BATCH * S_LEN * E_DIM;
    float* qb = (float*)d_ws;
    float* kb = qb + qkv_elems;
    float* vb = kb + qkv_elems;

    const int M = BATCH * S_LEN;              // 4096
    dim3 g1(M / 128, E_DIM / 128, 3);         // (32, 8, 3)
    qkv_gemm_kernel<<<g1, dim3(256), 0, stream>>>(x, Wq, bq, Wk, bk, Wv, bv,
                                                  qb, kb, vb);

    dim3 g2(BATCH * NHEAD, S_LEN / 64);       // (32, 32)
    attn_kernel<<<g2, dim3(256), 0, stream>>>(qb, kb, vb, out);
}

// Round 3
// 237.470 us; speedup vs baseline: 4.4942x; 4.4942x over previous
//
#include <hip/hip_runtime.h>
#include <hip/hip_bf16.h>
#include <stdint.h>

// Fixed problem shape: B=2, S=2048, E=1024, H=16, Dh=64, fp32 in/out.
#define S_LEN 2048
#define E_DIM 1024
#define NHEAD 16
#define DHEAD 64
#define BATCH 2

typedef short bf16x8 __attribute__((ext_vector_type(8)));  // 8 bf16 in 4 VGPRs
typedef float f32x4 __attribute__((ext_vector_type(4)));

__device__ __forceinline__ ushort f2bf(float f) {
    uint32_t u = __builtin_bit_cast(uint32_t, f);
    u += 0x7fffu + ((u >> 16) & 1u);       // round-to-nearest-even
    return (ushort)(u >> 16);
}
__device__ __forceinline__ float bf2f(ushort h) {
    uint32_t u = ((uint32_t)h) << 16;
    return __builtin_bit_cast(float, u);
}

// ---------------------------------------------------------------------------
// fp32 -> bf16 convert: blockIdx.y selects {x, Wq, Wk, Wv}
// ---------------------------------------------------------------------------
__global__ __launch_bounds__(256) void convert_kernel(
    const float* __restrict__ x, const float* __restrict__ wq,
    const float* __restrict__ wk, const float* __restrict__ wv,
    ushort* __restrict__ xb, ushort* __restrict__ wqb,
    ushort* __restrict__ wkb, ushort* __restrict__ wvb)
{
    const int a = blockIdx.y;
    const float* src = (a == 0) ? x : (a == 1) ? wq : (a == 2) ? wk : wv;
    ushort* dst      = (a == 0) ? xb : (a == 1) ? wqb : (a == 2) ? wkb : wvb;
    const int n4 = (a == 0) ? (BATCH * S_LEN * E_DIM / 4) : (E_DIM * E_DIM / 4);
    const int idx = blockIdx.x * 256 + threadIdx.x;
    if (idx < n4) {
        float4 v = reinterpret_cast<const float4*>(src)[idx];
        ushort4 o;
        o.x = f2bf(v.x); o.y = f2bf(v.y); o.z = f2bf(v.z); o.w = f2bf(v.w);
        reinterpret_cast<ushort4*>(dst)[idx] = o;
    }
}

// ---------------------------------------------------------------------------
// MFMA GEMM: C[i][j] = sum_k A[i][k]*B[j][k] (+bias), bf16 in, bf16 out.
// z=0: q = x·Wq^T  -> qb [B,H,S,Dh]        (A=x, B=Wq, bias over j)
// z=1: k = x·Wk^T  -> kb [B,H,S,Dh]
// z=2: v^T = Wv·x^T -> vtb [B,H,Dh,S]      (A=Wv, B=x, bias over i) coalesced
// 128x128 tile, BK=32, 4 waves (2x2), 4x4 frags of 16x16x32 per wave.
// ---------------------------------------------------------------------------
__global__ __launch_bounds__(256) void qkv_mfma_kernel(
    const ushort* __restrict__ xb, const ushort* __restrict__ wqb,
    const ushort* __restrict__ wkb, const ushort* __restrict__ wvb,
    const float* __restrict__ bq, const float* __restrict__ bk,
    const float* __restrict__ bv,
    ushort* __restrict__ qb, ushort* __restrict__ kb, ushort* __restrict__ vtb)
{
    const int z = blockIdx.z;
    const ushort* Ag; const ushort* Bg; const float* bias;
    int m0, n0;
    if (z == 2) { Ag = wvb; Bg = xb;                 bias = bv;
                  m0 = blockIdx.y * 128; n0 = blockIdx.x * 128; }
    else        { Ag = xb;  Bg = (z == 0) ? wqb : wkb; bias = (z == 0) ? bq : bk;
                  m0 = blockIdx.x * 128; n0 = blockIdx.y * 128; }

    // [128 rows][32 cols] bf16, rows are 64B; XOR-swizzle (((row>>1)&3)<<3)
    // in ushort units makes ds_read_b128 / ds_write_b128 conflict-free.
    __shared__ ushort As[128 * 32];
    __shared__ ushort Bs[128 * 32];

    const int tid  = threadIdx.x;
    const int lane = tid & 63;
    const int wid  = tid >> 6;
    const int wr   = wid >> 1, wc = wid & 1;

    f32x4 acc[4][4];
    #pragma unroll
    for (int i = 0; i < 4; ++i)
        #pragma unroll
        for (int j = 0; j < 4; ++j) acc[i][j] = (f32x4){0.f, 0.f, 0.f, 0.f};

    const int srow0 = tid >> 2;           // staging: 4 lanes x 16B per row
    const int scol  = (tid & 3) * 8;
    const int lr    = lane & 15;
    const int lc    = (lane >> 4) * 8;

    for (int k0 = 0; k0 < E_DIM; k0 += 32) {
        #pragma unroll
        for (int p = 0; p < 2; ++p) {
            const int row = srow0 + p * 64;
            bf16x8 av = *reinterpret_cast<const bf16x8*>(
                &Ag[(size_t)(m0 + row) * E_DIM + k0 + scol]);
            bf16x8 bv8 = *reinterpret_cast<const bf16x8*>(
                &Bg[(size_t)(n0 + row) * E_DIM + k0 + scol]);
            const int sw = scol ^ (((row >> 1) & 3) << 3);
            *reinterpret_cast<bf16x8*>(&As[row * 32 + sw]) = av;
            *reinterpret_cast<bf16x8*>(&Bs[row * 32 + sw]) = bv8;
        }
        __syncthreads();

        bf16x8 af[4], bf[4];
        #pragma unroll
        for (int mi = 0; mi < 4; ++mi) {
            const int row = wr * 64 + mi * 16 + lr;
            af[mi] = *reinterpret_cast<const bf16x8*>(
                &As[row * 32 + (lc ^ (((row >> 1) & 3) << 3))]);
        }
        #pragma unroll
        for (int ni = 0; ni < 4; ++ni) {
            const int row = wc * 64 + ni * 16 + lr;
            bf[ni] = *reinterpret_cast<const bf16x8*>(
                &Bs[row * 32 + (lc ^ (((row >> 1) & 3) << 3))]);
        }
        #pragma unroll
        for (int mi = 0; mi < 4; ++mi)
            #pragma unroll
            for (int ni = 0; ni < 4; ++ni)
                acc[mi][ni] = __builtin_amdgcn_mfma_f32_16x16x32_bf16(
                    af[mi], bf[ni], acc[mi][ni], 0, 0, 0);
        __syncthreads();
    }

    // epilogue: C/D layout col = lane&15, row = (lane>>4)*4 + reg
    const int rq = lane >> 4;
    #pragma unroll
    for (int mi = 0; mi < 4; ++mi) {
        #pragma unroll
        for (int ni = 0; ni < 4; ++ni) {
            #pragma unroll
            for (int r = 0; r < 4; ++r) {
                const int i = m0 + wr * 64 + mi * 16 + rq * 4 + r;
                const int j = n0 + wc * 64 + ni * 16 + lr;
                float val = acc[mi][ni][r];
                if (z == 2) {
                    val += bias[i];
                    const int h = i >> 6, d = i & 63;
                    const int b = j >> 11, s = j & (S_LEN - 1);
                    vtb[(((size_t)(b * NHEAD + h)) * DHEAD + d) * S_LEN + s] = f2bf(val);
                } else {
                    val += bias[j];
                    const int h = j >> 6, d = j & 63;
                    const int b = i >> 11, s = i & (S_LEN - 1);
                    ushort* o = (z == 0) ? qb : kb;
                    o[(((size_t)(b * NHEAD + h)) * S_LEN + s) * DHEAD + d] = f2bf(val);
                }
            }
        }
    }
}

// ---------------------------------------------------------------------------
// MFMA flash attention. Block: one (b,h), 64 q-rows; 4 waves x 16 q-rows.
// KV tiles of 64. QK^T and PV via mfma_f32_16x16x32_bf16, online softmax.
// All LDS tiles [*][64] bf16 with byte^=((row&7)<<4) swizzle (G4).
// ---------------------------------------------------------------------------
__global__ __launch_bounds__(256) void attn_mfma_kernel(
    const ushort* __restrict__ qb, const ushort* __restrict__ kb,
    const ushort* __restrict__ vtb, float* __restrict__ out)
{
    const int bh = blockIdx.x;
    const int q0 = blockIdx.y * 64;
    const int b = bh >> 4, h = bh & 15;
    const ushort* Q  = qb  + (size_t)bh * S_LEN * DHEAD;
    const ushort* K  = kb  + (size_t)bh * S_LEN * DHEAD;
    const ushort* Vt = vtb + (size_t)bh * DHEAD * S_LEN;   // [Dh][S]

    __shared__ ushort Qs[64 * 64];
    __shared__ ushort Ks[64 * 64];
    __shared__ ushort Vs[64 * 64];        // V^T tile: [d][kv]
    __shared__ ushort Ps[4 * 16 * 64];    // per-wave P

    const int tid  = threadIdx.x;
    const int lane = tid & 63;
    const int wid  = tid >> 6;
    const int strow = tid >> 3;           // staging: 8 lanes x 16B per row
    const int stcol = (tid & 7) * 8;
    const int lr = lane & 15;
    const int lc = (lane >> 4) * 8;
    const int rq = lane >> 4;

    // stage Q tile once
    #pragma unroll
    for (int p = 0; p < 2; ++p) {
        const int row = strow + p * 32;
        bf16x8 v = *reinterpret_cast<const bf16x8*>(
            &Q[(size_t)(q0 + row) * DHEAD + stcol]);
        *reinterpret_cast<bf16x8*>(&Qs[row * 64 + (stcol ^ ((row & 7) << 3))]) = v;
    }
    __syncthreads();

    bf16x8 qf[2];
    #pragma unroll
    for (int ks = 0; ks < 2; ++ks) {
        const int row = wid * 16 + lr;
        const int col = ks * 32 + lc;
        qf[ks] = *reinterpret_cast<const bf16x8*>(
            &Qs[row * 64 + (col ^ ((row & 7) << 3))]);
    }

    float m_run[4], l_run[4];
    f32x4 oacc[4];
    #pragma unroll
    for (int r = 0; r < 4; ++r) { m_run[r] = -1e30f; l_run[r] = 0.f; }
    #pragma unroll
    for (int df = 0; df < 4; ++df) oacc[df] = (f32x4){0.f, 0.f, 0.f, 0.f};

    ushort* Pw = &Ps[wid * 16 * 64];

    for (int t0 = 0; t0 < S_LEN; t0 += 64) {
        // stage K tile [kv][d] and V^T tile [d][kv]
        #pragma unroll
        for (int p = 0; p < 2; ++p) {
            const int row = strow + p * 32;
            bf16x8 kv = *reinterpret_cast<const bf16x8*>(
                &K[(size_t)(t0 + row) * DHEAD + stcol]);
            bf16x8 vv = *reinterpret_cast<const bf16x8*>(
                &Vt[(size_t)row * S_LEN + t0 + stcol]);
            const int sw = row * 64 + (stcol ^ ((row & 7) << 3));
            *reinterpret_cast<bf16x8*>(&Ks[sw]) = kv;
            *reinterpret_cast<bf16x8*>(&Vs[sw]) = vv;
        }
        __syncthreads();

        // QK^T: S tile 16(q) x 64(kv) per wave
        f32x4 sacc[4];
        #pragma unroll
        for (int nf = 0; nf < 4; ++nf) sacc[nf] = (f32x4){0.f, 0.f, 0.f, 0.f};
        #pragma unroll
        for (int nf = 0; nf < 4; ++nf) {
            #pragma unroll
            for (int ks = 0; ks < 2; ++ks) {
                const int row = nf * 16 + lr;
                const int col = ks * 32 + lc;
                bf16x8 kf = *reinterpret_cast<const bf16x8*>(
                    &Ks[row * 64 + (col ^ ((row & 7) << 3))]);
                sacc[nf] = __builtin_amdgcn_mfma_f32_16x16x32_bf16(
                    qf[ks], kf, sacc[nf], 0, 0, 0);
            }
        }

        // online softmax; lane holds q=(rq*4+r), k=nf*16+lr
        float alpha[4];
        #pragma unroll
        for (int r = 0; r < 4; ++r) {
            float mt = fmaxf(fmaxf(sacc[0][r], sacc[1][r]),
                             fmaxf(sacc[2][r], sacc[3][r])) * 0.125f;
            mt = fmaxf(mt, __shfl_xor(mt, 1));
            mt = fmaxf(mt, __shfl_xor(mt, 2));
            mt = fmaxf(mt, __shfl_xor(mt, 4));
            mt = fmaxf(mt, __shfl_xor(mt, 8));
            const float mn = fmaxf(m_run[r], mt);
            alpha[r] = __expf(m_run[r] - mn);
            m_run[r] = mn;
            const int q = rq * 4 + r;
            float lsum = 0.f;
            #pragma unroll
            for (int nf = 0; nf < 4; ++nf) {
                const float pv = __expf(sacc[nf][r] * 0.125f - mn);
                const ushort pb = f2bf(pv);
                lsum += bf2f(pb);               // sum exactly what PV will use
                const int k = nf * 16 + lr;
                Pw[q * 64 + (k ^ ((q & 7) << 3))] = pb;
            }
            lsum += __shfl_xor(lsum, 1);
            lsum += __shfl_xor(lsum, 2);
            lsum += __shfl_xor(lsum, 4);
            lsum += __shfl_xor(lsum, 8);
            l_run[r] = l_run[r] * alpha[r] + lsum;
        }

        // PV: O tile 16(q) x 64(d) per wave; A=P[16x64], B=V^T[64d][64kv]
        bf16x8 pf[2];
        #pragma unroll
        for (int ks = 0; ks < 2; ++ks) {
            const int col = ks * 32 + lc;
            pf[ks] = *reinterpret_cast<const bf16x8*>(
                &Pw[lr * 64 + (col ^ ((lr & 7) << 3))]);
        }
        #pragma unroll
        for (int df = 0; df < 4; ++df) {
            f32x4 t = oacc[df];
            #pragma unroll
            for (int r = 0; r < 4; ++r) t[r] *= alpha[r];
            #pragma unroll
            for (int ks = 0; ks < 2; ++ks) {
                const int row = df * 16 + lr;
                const int col = ks * 32 + lc;
                bf16x8 vf = *reinterpret_cast<const bf16x8*>(
                    &Vs[row * 64 + (col ^ ((row & 7) << 3))]);
                t = __builtin_amdgcn_mfma_f32_16x16x32_bf16(pf[ks], vf, t, 0, 0, 0);
            }
            oacc[df] = t;
        }
        __syncthreads();
    }

    // epilogue: out[B,S,E] fp32
    #pragma unroll
    for (int df = 0; df < 4; ++df) {
        #pragma unroll
        for (int r = 0; r < 4; ++r) {
            const int q = q0 + wid * 16 + rq * 4 + r;
            const int d = df * 16 + lr;
            out[((size_t)(b * S_LEN + q)) * E_DIM + h * DHEAD + d] =
                oacc[df][r] / l_run[r];
        }
    }
}

// ---------------------------------------------------------------------------
extern "C" void kernel_launch(void* const* d_in, const int* in_sizes, int n_in,
                              void* d_out, int out_size, void* d_ws, size_t ws_size,
                              hipStream_t stream) {
    const float* x  = (const float*)d_in[0];
    const float* Wq = (const float*)d_in[1];
    const float* bq = (const float*)d_in[2];
    const float* Wk = (const float*)d_in[3];
    const float* bk = (const float*)d_in[4];
    const float* Wv = (const float*)d_in[5];
    const float* bv = (const float*)d_in[6];
    float* out = (float*)d_out;

    const size_t XN = (size_t)BATCH * S_LEN * E_DIM;   // 4M elems
    const size_t WN = (size_t)E_DIM * E_DIM;           // 1M elems
    ushort* xb  = (ushort*)d_ws;
    ushort* wqb = xb  + XN;
    ushort* wkb = wqb + WN;
    ushort* wvb = wkb + WN;
    ushort* qbb = wvb + WN;
    ushort* kbb = qbb + XN;
    ushort* vtb = kbb + XN;   // total ~38 MB

    convert_kernel<<<dim3(4096, 4), 256, 0, stream>>>(
        x, Wq, Wk, Wv, xb, wqb, wkb, wvb);

    qkv_mfma_kernel<<<dim3(32, 8, 3), 256, 0, stream>>>(
        xb, wqb, wkb, wvb, bq, bk, bv, qbb, kbb, vtb);

    attn_mfma_kernel<<<dim3(BATCH * NHEAD, S_LEN / 64), 256, 0, stream>>>(
        qbb, kbb, vtb, out);
}

// Round 8
// 212.737 us; speedup vs baseline: 5.0167x; 1.1163x over previous
//
#include <hip/hip_runtime.h>
#include <hip/hip_bf16.h>
#include <stdint.h>

// Fixed problem shape: B=2, S=2048, E=1024, H=16, Dh=64, fp32 in/out.
#define S_LEN 2048
#define E_DIM 1024
#define NHEAD 16
#define DHEAD 64
#define BATCH 2

typedef short bf16x8 __attribute__((ext_vector_type(8)));  // 8 bf16 in 4 VGPRs
typedef float f32x4 __attribute__((ext_vector_type(4)));
typedef float f32x16 __attribute__((ext_vector_type(16)));

__device__ __forceinline__ ushort f2bf(float f) {
    uint32_t u = __builtin_bit_cast(uint32_t, f);
    u += 0x7fffu + ((u >> 16) & 1u);       // round-to-nearest-even
    return (ushort)(u >> 16);
}
__device__ __forceinline__ float bf2f(ushort h) {
    uint32_t u = ((uint32_t)h) << 16;
    return __builtin_bit_cast(float, u);
}
__device__ __forceinline__ uint32_t packbf2(float a, float b) {
    // RNE pack: a in low 16, b in high 16 (same semantics as cvt_pk_bf16_f32)
    return (uint32_t)f2bf(a) | ((uint32_t)f2bf(b) << 16);
}
__device__ __forceinline__ f32x16 zero16() {
    f32x16 v;
    #pragma unroll
    for (int i = 0; i < 16; ++i) v[i] = 0.f;
    return v;
}

// ---------------------------------------------------------------------------
// fp32 -> bf16 convert: blockIdx.y selects {x, Wq, Wk, Wv}
// ---------------------------------------------------------------------------
__global__ __launch_bounds__(256) void convert_kernel(
    const float* __restrict__ x, const float* __restrict__ wq,
    const float* __restrict__ wk, const float* __restrict__ wv,
    ushort* __restrict__ xb, ushort* __restrict__ wqb,
    ushort* __restrict__ wkb, ushort* __restrict__ wvb)
{
    const int a = blockIdx.y;
    const float* src = (a == 0) ? x : (a == 1) ? wq : (a == 2) ? wk : wv;
    ushort* dst      = (a == 0) ? xb : (a == 1) ? wqb : (a == 2) ? wkb : wvb;
    const int n4 = (a == 0) ? (BATCH * S_LEN * E_DIM / 4) : (E_DIM * E_DIM / 4);
    const int idx = blockIdx.x * 256 + threadIdx.x;
    if (idx < n4) {
        float4 v = reinterpret_cast<const float4*>(src)[idx];
        ushort4 o;
        o.x = f2bf(v.x); o.y = f2bf(v.y); o.z = f2bf(v.z); o.w = f2bf(v.w);
        reinterpret_cast<ushort4*>(dst)[idx] = o;
    }
}

// ---------------------------------------------------------------------------
// MFMA GEMM (unchanged): C[i][j] = sum_k A[i][k]*B[j][k] (+bias)
// z=0: q = x·Wq^T -> qb [B,H,S,Dh]; z=1: k -> kb; z=2: v^T = Wv·x^T -> vtb [B,H,Dh,S]
// ---------------------------------------------------------------------------
__global__ __launch_bounds__(256) void qkv_mfma_kernel(
    const ushort* __restrict__ xb, const ushort* __restrict__ wqb,
    const ushort* __restrict__ wkb, const ushort* __restrict__ wvb,
    const float* __restrict__ bq, const float* __restrict__ bk,
    const float* __restrict__ bv,
    ushort* __restrict__ qb, ushort* __restrict__ kb, ushort* __restrict__ vtb)
{
    const int z = blockIdx.z;
    const ushort* Ag; const ushort* Bg; const float* bias;
    int m0, n0;
    if (z == 2) { Ag = wvb; Bg = xb;                 bias = bv;
                  m0 = blockIdx.y * 128; n0 = blockIdx.x * 128; }
    else        { Ag = xb;  Bg = (z == 0) ? wqb : wkb; bias = (z == 0) ? bq : bk;
                  m0 = blockIdx.x * 128; n0 = blockIdx.y * 128; }

    __shared__ ushort As[128 * 32];
    __shared__ ushort Bs[128 * 32];

    const int tid  = threadIdx.x;
    const int lane = tid & 63;
    const int wid  = tid >> 6;
    const int wr   = wid >> 1, wc = wid & 1;

    f32x4 acc[4][4];
    #pragma unroll
    for (int i = 0; i < 4; ++i)
        #pragma unroll
        for (int j = 0; j < 4; ++j) acc[i][j] = (f32x4){0.f, 0.f, 0.f, 0.f};

    const int srow0 = tid >> 2;
    const int scol  = (tid & 3) * 8;
    const int lr    = lane & 15;
    const int lc    = (lane >> 4) * 8;

    for (int k0 = 0; k0 < E_DIM; k0 += 32) {
        #pragma unroll
        for (int p = 0; p < 2; ++p) {
            const int row = srow0 + p * 64;
            bf16x8 av = *reinterpret_cast<const bf16x8*>(
                &Ag[(size_t)(m0 + row) * E_DIM + k0 + scol]);
            bf16x8 bv8 = *reinterpret_cast<const bf16x8*>(
                &Bg[(size_t)(n0 + row) * E_DIM + k0 + scol]);
            const int sw = scol ^ (((row >> 1) & 3) << 3);
            *reinterpret_cast<bf16x8*>(&As[row * 32 + sw]) = av;
            *reinterpret_cast<bf16x8*>(&Bs[row * 32 + sw]) = bv8;
        }
        __syncthreads();

        bf16x8 af[4], bf[4];
        #pragma unroll
        for (int mi = 0; mi < 4; ++mi) {
            const int row = wr * 64 + mi * 16 + lr;
            af[mi] = *reinterpret_cast<const bf16x8*>(
                &As[row * 32 + (lc ^ (((row >> 1) & 3) << 3))]);
        }
        #pragma unroll
        for (int ni = 0; ni < 4; ++ni) {
            const int row = wc * 64 + ni * 16 + lr;
            bf[ni] = *reinterpret_cast<const bf16x8*>(
                &Bs[row * 32 + (lc ^ (((row >> 1) & 3) << 3))]);
        }
        #pragma unroll
        for (int mi = 0; mi < 4; ++mi)
            #pragma unroll
            for (int ni = 0; ni < 4; ++ni)
                acc[mi][ni] = __builtin_amdgcn_mfma_f32_16x16x32_bf16(
                    af[mi], bf[ni], acc[mi][ni], 0, 0, 0);
        __syncthreads();
    }

    const int rq = lane >> 4;
    #pragma unroll
    for (int mi = 0; mi < 4; ++mi) {
        #pragma unroll
        for (int ni = 0; ni < 4; ++ni) {
            #pragma unroll
            for (int r = 0; r < 4; ++r) {
                const int i = m0 + wr * 64 + mi * 16 + rq * 4 + r;
                const int j = n0 + wc * 64 + ni * 16 + lr;
                float val = acc[mi][ni][r];
                if (z == 2) {
                    val += bias[i];
                    const int h = i >> 6, d = i & 63;
                    const int b = j >> 11, s = j & (S_LEN - 1);
                    vtb[(((size_t)(b * NHEAD + h)) * DHEAD + d) * S_LEN + s] = f2bf(val);
                } else {
                    val += bias[j];
                    const int h = j >> 6, d = j & 63;
                    const int b = i >> 11, s = i & (S_LEN - 1);
                    ushort* o = (z == 0) ? qb : kb;
                    o[(((size_t)(b * NHEAD + h)) * S_LEN + s) * DHEAD + d] = f2bf(val);
                }
            }
        }
    }
}

// ---------------------------------------------------------------------------
// Attention v2: 32x32 MFMA, swapped operands, in-register softmax (m214 port).
// Block = 4 waves x 32 q-rows = 128 q; KV tiles of 64. Per wave:
//   QK^T: sacc[t] = mfma(K_frag, Q_frag) -> C[kv][q], q = lane&31 (lane-local!)
//   softmax: 31 in-reg fmax + 1 shfl_xor(32); exp2-domain; defer-max THR=8
//   P: RNE pack pairs + shfl_xor(32)-swap -> PV B-frags, fully in-register
//   PV: oacc[dblk] = mfma(Vt_frag, P_frag) -> C[d][q]; rescale/normalize lane-local
// LDS: 16 KB (Q stage reused as K|V^T tiles), byte^((row&7)<<4) swizzle.
// ---------------------------------------------------------------------------
__global__ __launch_bounds__(256) void attn_mfma32_kernel(
    const ushort* __restrict__ qb, const ushort* __restrict__ kb,
    const ushort* __restrict__ vtb, float* __restrict__ out)
{
    // XCD-aware bijective swizzle: 512 blocks, same-head blocks share an XCD's L2
    const int bid = blockIdx.x;
    const int swzb = (bid & 7) * 64 + (bid >> 3);
    const int bh = swzb >> 4;            // 0..31
    const int q0 = (swzb & 15) * 128;
    const int b = bh >> 4, h = bh & 15;
    const ushort* Q  = qb  + (size_t)bh * S_LEN * DHEAD;
    const ushort* K  = kb  + (size_t)bh * S_LEN * DHEAD;
    const ushort* Vt = vtb + (size_t)bh * DHEAD * S_LEN;   // [Dh][S]

    __shared__ ushort smem[128 * 64];    // 16 KB
    ushort* Ks = smem;                   // [64 kv][64 d] swizzled
    ushort* Vs = smem + 64 * 64;         // [64 d][64 kv] swizzled

    const int tid  = threadIdx.x;
    const int lane = tid & 63;
    const int wid  = tid >> 6;
    const int hi   = lane >> 5;          // k-half selector in A/B frags
    const int l31  = lane & 31;
    const int swzr = (lane & 7) << 3;    // frag-read swizzle (ushort units)
    const float CSCALE = 0.125f * 1.4426950408889634f;   // /sqrt(64) * log2(e)

    // ---- stage Q [128][64] swizzled, then hoist per-wave Q-frags ----
    {
        const int slot = (tid & 7) * 8;
        #pragma unroll
        for (int p = 0; p < 4; ++p) {
            const int row = (tid >> 3) + p * 32;
            bf16x8 v = *reinterpret_cast<const bf16x8*>(
                &Q[(size_t)(q0 + row) * DHEAD + slot]);
            *reinterpret_cast<bf16x8*>(
                &smem[row * 64 + (slot ^ ((row & 7) << 3))]) = v;
        }
    }
    __syncthreads();

    bf16x8 qf[4];
    {
        const int qrow = wid * 32 + l31;
        #pragma unroll
        for (int st = 0; st < 4; ++st)
            qf[st] = *reinterpret_cast<const bf16x8*>(
                &smem[qrow * 64 + ((st * 16 + hi * 8) ^ swzr)]);
    }

    float m_run = -1e30f, l_run = 0.f;
    f32x16 oacc[2] = {zero16(), zero16()};

    const int stslot = (tid & 7) * 8;
    const int strow  = tid >> 3;         // 0..31

    for (int t0 = 0; t0 < S_LEN; t0 += 64) {
        __syncthreads();                 // prior tile's LDS reads complete
        #pragma unroll
        for (int p = 0; p < 2; ++p) {
            const int row = strow + p * 32;
            const int sw  = row * 64 + (stslot ^ ((row & 7) << 3));
            bf16x8 kv8 = *reinterpret_cast<const bf16x8*>(
                &K[(size_t)(t0 + row) * DHEAD + stslot]);
            bf16x8 vv8 = *reinterpret_cast<const bf16x8*>(
                &Vt[(size_t)row * S_LEN + t0 + stslot]);
            *reinterpret_cast<bf16x8*>(&Ks[sw]) = kv8;
            *reinterpret_cast<bf16x8*>(&Vs[sw]) = vv8;
        }
        __syncthreads();

        // ---- swapped QK^T: C[row=kv][col=q] ----
        f32x16 sacc[2] = {zero16(), zero16()};
        #pragma unroll
        for (int t = 0; t < 2; ++t) {
            const int kbase = (t * 32 + l31) * 64;
            #pragma unroll
            for (int st = 0; st < 4; ++st) {
                bf16x8 kf = *reinterpret_cast<const bf16x8*>(
                    &Ks[kbase + ((st * 16 + hi * 8) ^ swzr)]);
                sacc[t] = __builtin_amdgcn_mfma_f32_32x32x16_bf16(
                    kf, qf[st], sacc[t], 0, 0, 0);
            }
        }

        // ---- in-register softmax (q = lane&31 is lane-local) ----
        float mx = sacc[0][0];
        #pragma unroll
        for (int r = 1; r < 16; ++r) mx = fmaxf(mx, sacc[0][r]);
        #pragma unroll
        for (int r = 0; r < 16; ++r) mx = fmaxf(mx, sacc[1][r]);
        mx = fmaxf(mx, __shfl_xor(mx, 32));
        const float mt = mx * CSCALE;

        if (__any(mt > m_run + 8.0f)) {          // defer-max (T13)
            const float mn = fmaxf(m_run, mt);
            const float al = exp2f(m_run - mn);
            m_run = mn;
            l_run *= al;
            #pragma unroll
            for (int r = 0; r < 16; ++r) { oacc[0][r] *= al; oacc[1][r] *= al; }
        }

        // ---- p = exp2(s*C - m), pack to bf16 pairs, swap-across-hi -> P frags
        float lsum = 0.f;
        uint32_t w[4][4];                        // [chunk][word] PV B-frag words
        #pragma unroll
        for (int t = 0; t < 2; ++t) {
            #pragma unroll
            for (int half = 0; half < 2; ++half) {
                float p[8];
                #pragma unroll
                for (int j = 0; j < 8; ++j) {
                    p[j] = exp2f(fmaf(sacc[t][half * 8 + j], CSCALE, -m_run));
                    lsum += p[j];
                }
                const uint32_t a0 = packbf2(p[0], p[1]);
                const uint32_t a1 = packbf2(p[2], p[3]);
                const uint32_t b0 = packbf2(p[4], p[5]);
                const uint32_t b1 = packbf2(p[6], p[7]);
                const uint32_t xs0 = __shfl_xor(a0, 32);
                const uint32_t ys0 = __shfl_xor(b0, 32);
                const uint32_t xs1 = __shfl_xor(a1, 32);
                const uint32_t ys1 = __shfl_xor(b1, 32);
                const int c = t * 2 + half;
                w[c][0] = hi ? ys0 : a0;
                w[c][2] = hi ? b0  : xs0;
                w[c][1] = hi ? ys1 : a1;
                w[c][3] = hi ? b1  : xs1;
            }
        }
        lsum += __shfl_xor(lsum, 32);
        l_run += lsum;

        // ---- PV (swapped): oacc[dblk] += mfma(Vt_frag, P_frag) -> C[d][q] ----
        #pragma unroll
        for (int c = 0; c < 4; ++c) {
            union { uint32_t u[4]; bf16x8 v; } pf;
            pf.u[0] = w[c][0]; pf.u[1] = w[c][1];
            pf.u[2] = w[c][2]; pf.u[3] = w[c][3];
            #pragma unroll
            for (int dblk = 0; dblk < 2; ++dblk) {
                const int vrow = dblk * 32 + l31;
                bf16x8 vf = *reinterpret_cast<const bf16x8*>(
                    &Vs[vrow * 64 + ((c * 16 + hi * 8) ^ swzr)]);
                oacc[dblk] = __builtin_amdgcn_mfma_f32_32x32x16_bf16(
                    vf, pf.v, oacc[dblk], 0, 0, 0);
            }
        }
    }

    // ---- epilogue: out[b][q][h*64+d], d = (r&3)+8*(r>>2)+4*hi+32*dblk ----
    const float inv = 1.f / l_run;
    const int qg = q0 + wid * 32 + l31;
    float* obase = &out[((size_t)(b * S_LEN + qg)) * E_DIM + h * DHEAD];
    #pragma unroll
    for (int dblk = 0; dblk < 2; ++dblk) {
        #pragma unroll
        for (int g = 0; g < 4; ++g) {
            float4 f;
            f.x = oacc[dblk][g * 4 + 0] * inv;
            f.y = oacc[dblk][g * 4 + 1] * inv;
            f.z = oacc[dblk][g * 4 + 2] * inv;
            f.w = oacc[dblk][g * 4 + 3] * inv;
            *reinterpret_cast<float4*>(&obase[dblk * 32 + g * 8 + hi * 4]) = f;
        }
    }
}

// ---------------------------------------------------------------------------
extern "C" void kernel_launch(void* const* d_in, const int* in_sizes, int n_in,
                              void* d_out, int out_size, void* d_ws, size_t ws_size,
                              hipStream_t stream) {
    const float* x  = (const float*)d_in[0];
    const float* Wq = (const float*)d_in[1];
    const float* bq = (const float*)d_in[2];
    const float* Wk = (const float*)d_in[3];
    const float* bk = (const float*)d_in[4];
    const float* Wv = (const float*)d_in[5];
    const float* bv = (const float*)d_in[6];
    float* out = (float*)d_out;

    const size_t XN = (size_t)BATCH * S_LEN * E_DIM;   // 4M elems
    const size_t WN = (size_t)E_DIM * E_DIM;           // 1M elems
    ushort* xb  = (ushort*)d_ws;
    ushort* wqb = xb  + XN;
    ushort* wkb = wqb + WN;
    ushort* wvb = wkb + WN;
    ushort* qbb = wvb + WN;
    ushort* kbb = qbb + XN;
    ushort* vtb = kbb + XN;   // total ~38 MB

    convert_kernel<<<dim3(4096, 4), 256, 0, stream>>>(
        x, Wq, Wk, Wv, xb, wqb, wkb, wvb);

    qkv_mfma_kernel<<<dim3(32, 8, 3), 256, 0, stream>>>(
        xb, wqb, wkb, wvb, bq, bk, bv, qbb, kbb, vtb);

    attn_mfma32_kernel<<<dim3(512), 256, 0, stream>>>(qbb, kbb, vtb, out);
}

// Round 11
// 195.435 us; speedup vs baseline: 5.4609x; 1.0885x over previous
//
#include <hip/hip_runtime.h>
#include <hip/hip_bf16.h>
#include <stdint.h>

// Fixed problem shape: B=2, S=2048, E=1024, H=16, Dh=64, fp32 in/out.
#define S_LEN 2048
#define E_DIM 1024
#define NHEAD 16
#define DHEAD 64
#define BATCH 2

typedef short bf16x8 __attribute__((ext_vector_type(8)));  // 8 bf16 in 4 VGPRs
typedef float f32x4 __attribute__((ext_vector_type(4)));
typedef float f32x16 __attribute__((ext_vector_type(16)));

__device__ __forceinline__ ushort f2bf(float f) {
    uint32_t u = __builtin_bit_cast(uint32_t, f);
    u += 0x7fffu + ((u >> 16) & 1u);       // round-to-nearest-even
    return (ushort)(u >> 16);
}
__device__ __forceinline__ uint32_t cvtpk(float lo, float hi) {
    // single-instruction RNE pack: lo -> [15:0], hi -> [31:16]
    uint32_t r;
    asm("v_cvt_pk_bf16_f32 %0, %1, %2" : "=v"(r) : "v"(lo), "v"(hi));
    return r;
}
__device__ __forceinline__ f32x16 zero16() {
    f32x16 v;
    #pragma unroll
    for (int i = 0; i < 16; ++i) v[i] = 0.f;
    return v;
}
// async global->LDS DMA, 16B per lane; LDS dst must be wave-uniform base
__device__ __forceinline__ void gload16(const void* g, void* l) {
    __builtin_amdgcn_global_load_lds(
        (const __attribute__((address_space(1))) uint32_t*)g,
        (__attribute__((address_space(3))) uint32_t*)l, 16, 0, 0);
}

// ---------------------------------------------------------------------------
// fp32 -> bf16 convert: blockIdx.y selects {x, Wq, Wk, Wv}
// ---------------------------------------------------------------------------
__global__ __launch_bounds__(256) void convert_kernel(
    const float* __restrict__ x, const float* __restrict__ wq,
    const float* __restrict__ wk, const float* __restrict__ wv,
    ushort* __restrict__ xb, ushort* __restrict__ wqb,
    ushort* __restrict__ wkb, ushort* __restrict__ wvb)
{
    const int a = blockIdx.y;
    const float* src = (a == 0) ? x : (a == 1) ? wq : (a == 2) ? wk : wv;
    ushort* dst      = (a == 0) ? xb : (a == 1) ? wqb : (a == 2) ? wkb : wvb;
    const int n4 = (a == 0) ? (BATCH * S_LEN * E_DIM / 4) : (E_DIM * E_DIM / 4);
    const int idx = blockIdx.x * 256 + threadIdx.x;
    if (idx < n4) {
        float4 v = reinterpret_cast<const float4*>(src)[idx];
        ushort4 o;
        o.x = f2bf(v.x); o.y = f2bf(v.y); o.z = f2bf(v.z); o.w = f2bf(v.w);
        reinterpret_cast<ushort4*>(dst)[idx] = o;
    }
}

// ---------------------------------------------------------------------------
// MFMA GEMM, m97-style: global_load_lds width-16 staging, linear [128][32] LDS.
// C[i][j] = sum_k A[i][k]*B[j][k] (+bias)
// z=0: q = x·Wq^T -> qb [B,H,S,Dh]; z=1: k -> kb; z=2: v^T = Wv·x^T -> vtb [B,H,Dh,S]
// 128x128 tile, BK=32, 4 waves (2x2), 4x4 frags of 16x16x32 per wave.
// ---------------------------------------------------------------------------
__global__ __launch_bounds__(256) void qkv_mfma_kernel(
    const ushort* __restrict__ xb, const ushort* __restrict__ wqb,
    const ushort* __restrict__ wkb, const ushort* __restrict__ wvb,
    const float* __restrict__ bq, const float* __restrict__ bk,
    const float* __restrict__ bv,
    ushort* __restrict__ qb, ushort* __restrict__ kb, ushort* __restrict__ vtb)
{
    const int z = blockIdx.z;
    const ushort* Ag; const ushort* Bg; const float* bias;
    int m0, n0;
    if (z == 2) { Ag = wvb; Bg = xb;                 bias = bv;
                  m0 = blockIdx.y * 128; n0 = blockIdx.x * 128; }
    else        { Ag = xb;  Bg = (z == 0) ? wqb : wkb; bias = (z == 0) ? bq : bk;
                  m0 = blockIdx.x * 128; n0 = blockIdx.y * 128; }

    __shared__ ushort As[128 * 32];   // linear: row*32 + col (rows of 64B)
    __shared__ ushort Bs[128 * 32];

    const int tid  = threadIdx.x;
    const int lane = tid & 63;
    const int wid  = tid >> 6;
    const int wr   = wid >> 1, wc = wid & 1;

    f32x4 acc[4][4];
    #pragma unroll
    for (int i = 0; i < 4; ++i)
        #pragma unroll
        for (int j = 0; j < 4; ++j) acc[i][j] = (f32x4){0.f, 0.f, 0.f, 0.f};

    // gload_lds lane mapping: 64 lanes x 16B -> 16 rows x 64B contiguous chunk.
    const int grow = lane >> 2;          // 0..15 row within chunk
    const int gcol = (lane & 3) * 8;     // ushort col
    const int lr   = lane & 15;
    const int lc   = (lane >> 4) * 8;

    for (int k0 = 0; k0 < E_DIM; k0 += 32) {
        // wave w stages rows [w*32, w*32+32) of A and B: 2 chunks each
        #pragma unroll
        for (int j = 0; j < 2; ++j) {
            const int rbase = wid * 32 + j * 16;
            gload16(&Ag[(size_t)(m0 + rbase + grow) * E_DIM + k0 + gcol],
                    &As[rbase * 32]);
            gload16(&Bg[(size_t)(n0 + rbase + grow) * E_DIM + k0 + gcol],
                    &Bs[rbase * 32]);
        }
        __syncthreads();   // drains vmcnt (gload_lds) + lgkm

        bf16x8 af[4], bf[4];
        #pragma unroll
        for (int mi = 0; mi < 4; ++mi)
            af[mi] = *reinterpret_cast<const bf16x8*>(
                &As[(wr * 64 + mi * 16 + lr) * 32 + lc]);
        #pragma unroll
        for (int ni = 0; ni < 4; ++ni)
            bf[ni] = *reinterpret_cast<const bf16x8*>(
                &Bs[(wc * 64 + ni * 16 + lr) * 32 + lc]);
        #pragma unroll
        for (int mi = 0; mi < 4; ++mi)
            #pragma unroll
            for (int ni = 0; ni < 4; ++ni)
                acc[mi][ni] = __builtin_amdgcn_mfma_f32_16x16x32_bf16(
                    af[mi], bf[ni], acc[mi][ni], 0, 0, 0);
        __syncthreads();
    }

    const int rq = lane >> 4;
    #pragma unroll
    for (int mi = 0; mi < 4; ++mi) {
        #pragma unroll
        for (int ni = 0; ni < 4; ++ni) {
            #pragma unroll
            for (int r = 0; r < 4; ++r) {
                const int i = m0 + wr * 64 + mi * 16 + rq * 4 + r;
                const int j = n0 + wc * 64 + ni * 16 + lr;
                float val = acc[mi][ni][r];
                if (z == 2) {
                    val += bias[i];
                    const int h = i >> 6, d = i & 63;
                    const int b = j >> 11, s = j & (S_LEN - 1);
                    vtb[(((size_t)(b * NHEAD + h)) * DHEAD + d) * S_LEN + s] = f2bf(val);
                } else {
                    val += bias[j];
                    const int h = j >> 6, d = j & 63;
                    const int b = i >> 11, s = i & (S_LEN - 1);
                    ushort* o = (z == 0) ? qb : kb;
                    o[(((size_t)(b * NHEAD + h)) * S_LEN + s) * DHEAD + d] = f2bf(val);
                }
            }
        }
    }
}

// ---------------------------------------------------------------------------
// Attention v3: v2 structure + double-buffered K/V LDS with T14 async-stage
// (issue tile t+1 loads before compute(t); ds_write after the post-compute
// barrier) + cvt_pk bf16 packing.
// Block = 4 waves x 32 q-rows = 128 q; KV tiles of 64.
// ---------------------------------------------------------------------------
__global__ __launch_bounds__(256) void attn_mfma32_kernel(
    const ushort* __restrict__ qb, const ushort* __restrict__ kb,
    const ushort* __restrict__ vtb, float* __restrict__ out)
{
    // XCD-aware bijective swizzle: 512 blocks, same-head blocks share an XCD's L2
    const int bid = blockIdx.x;
    const int swzb = (bid & 7) * 64 + (bid >> 3);
    const int bh = swzb >> 4;            // 0..31
    const int q0 = (swzb & 15) * 128;
    const int b = bh >> 4, h = bh & 15;
    const ushort* Q  = qb  + (size_t)bh * S_LEN * DHEAD;
    const ushort* K  = kb  + (size_t)bh * S_LEN * DHEAD;
    const ushort* Vt = vtb + (size_t)bh * DHEAD * S_LEN;   // [Dh][S]

    __shared__ ushort Qs[128 * 64];      // 16 KB
    __shared__ ushort KV[2][2 * 64 * 64];// 2 x (Ks 8KB | Vs 8KB) = 32 KB

    const int tid  = threadIdx.x;
    const int lane = tid & 63;
    const int wid  = tid >> 6;
    const int hi   = lane >> 5;          // k-half selector in A/B frags
    const int l31  = lane & 31;
    const int swzr = (lane & 7) << 3;    // frag-read swizzle (ushort units)
    const float CSCALE = 0.125f * 1.4426950408889634f;   // /sqrt(64) * log2(e)

    const int stslot = (tid & 7) * 8;    // staging: 8 lanes x 16B per row
    const int strow  = tid >> 3;         // 0..31

    // ---- stage Q [128][64] swizzled; overlap tile-0 K/V load issue ----
    {
        const int slot = (tid & 7) * 8;
        #pragma unroll
        for (int p = 0; p < 4; ++p) {
            const int row = (tid >> 3) + p * 32;
            bf16x8 v = *reinterpret_cast<const bf16x8*>(
                &Q[(size_t)(q0 + row) * DHEAD + slot]);
            *reinterpret_cast<bf16x8*>(
                &Qs[row * 64 + (slot ^ ((row & 7) << 3))]) = v;
        }
    }

    bf16x8 kreg[2], vreg[2];
    #pragma unroll
    for (int p = 0; p < 2; ++p) {        // issue tile-0 global loads
        const int row = strow + p * 32;
        kreg[p] = *reinterpret_cast<const bf16x8*>(
            &K[(size_t)row * DHEAD + stslot]);
        vreg[p] = *reinterpret_cast<const bf16x8*>(
            &Vt[(size_t)row * S_LEN + stslot]);
    }
    __syncthreads();                     // Qs visible

    bf16x8 qf[4];
    {
        const int qrow = wid * 32 + l31;
        #pragma unroll
        for (int st = 0; st < 4; ++st)
            qf[st] = *reinterpret_cast<const bf16x8*>(
                &Qs[qrow * 64 + ((st * 16 + hi * 8) ^ swzr)]);
    }

    // write tile 0 into buf 0
    #pragma unroll
    for (int p = 0; p < 2; ++p) {
        const int row = strow + p * 32;
        const int sw  = row * 64 + (stslot ^ ((row & 7) << 3));
        *reinterpret_cast<bf16x8*>(&KV[0][sw])           = kreg[p];
        *reinterpret_cast<bf16x8*>(&KV[0][64 * 64 + sw]) = vreg[p];
    }
    __syncthreads();

    float m_run = -1e30f, l_run = 0.f;
    f32x16 oacc[2] = {zero16(), zero16()};
    int cur = 0;

    for (int t0 = 0; t0 < S_LEN; t0 += 64) {
        const bool more = (t0 + 64 < S_LEN);
        if (more) {                      // T14: issue next-tile loads EARLY
            const int tn = t0 + 64;
            #pragma unroll
            for (int p = 0; p < 2; ++p) {
                const int row = strow + p * 32;
                kreg[p] = *reinterpret_cast<const bf16x8*>(
                    &K[(size_t)(tn + row) * DHEAD + stslot]);
                vreg[p] = *reinterpret_cast<const bf16x8*>(
                    &Vt[(size_t)row * S_LEN + tn + stslot]);
            }
        }

        const ushort* Ks = &KV[cur][0];
        const ushort* Vs = &KV[cur][64 * 64];

        // ---- swapped QK^T: C[row=kv][col=q] ----
        f32x16 sacc[2] = {zero16(), zero16()};
        #pragma unroll
        for (int t = 0; t < 2; ++t) {
            const int kbase = (t * 32 + l31) * 64;
            #pragma unroll
            for (int st = 0; st < 4; ++st) {
                bf16x8 kf = *reinterpret_cast<const bf16x8*>(
                    &Ks[kbase + ((st * 16 + hi * 8) ^ swzr)]);
                sacc[t] = __builtin_amdgcn_mfma_f32_32x32x16_bf16(
                    kf, qf[st], sacc[t], 0, 0, 0);
            }
        }

        // ---- in-register softmax (q = lane&31 is lane-local) ----
        float mx = sacc[0][0];
        #pragma unroll
        for (int r = 1; r < 16; ++r) mx = fmaxf(mx, sacc[0][r]);
        #pragma unroll
        for (int r = 0; r < 16; ++r) mx = fmaxf(mx, sacc[1][r]);
        mx = fmaxf(mx, __shfl_xor(mx, 32));
        const float mt = mx * CSCALE;

        if (__any(mt > m_run + 8.0f)) {          // defer-max (T13)
            const float mn = fmaxf(m_run, mt);
            const float al = exp2f(m_run - mn);
            m_run = mn;
            l_run *= al;
            #pragma unroll
            for (int r = 0; r < 16; ++r) { oacc[0][r] *= al; oacc[1][r] *= al; }
        }

        // ---- p = exp2(s*C - m); cvt_pk pairs; swap-across-hi -> P frags ----
        float lsum = 0.f;
        uint32_t w[4][4];                        // [chunk][word] PV B-frag words
        #pragma unroll
        for (int t = 0; t < 2; ++t) {
            #pragma unroll
            for (int half = 0; half < 2; ++half) {
                float p[8];
                #pragma unroll
                for (int j = 0; j < 8; ++j) {
                    p[j] = exp2f(fmaf(sacc[t][half * 8 + j], CSCALE, -m_run));
                    lsum += p[j];
                }
                const uint32_t a0 = cvtpk(p[0], p[1]);
                const uint32_t a1 = cvtpk(p[2], p[3]);
                const uint32_t b0 = cvtpk(p[4], p[5]);
                const uint32_t b1 = cvtpk(p[6], p[7]);
                const uint32_t xs0 = __shfl_xor(a0, 32);
                const uint32_t ys0 = __shfl_xor(b0, 32);
                const uint32_t xs1 = __shfl_xor(a1, 32);
                const uint32_t ys1 = __shfl_xor(b1, 32);
                const int c = t * 2 + half;
                w[c][0] = hi ? ys0 : a0;
                w[c][2] = hi ? b0  : xs0;
                w[c][1] = hi ? ys1 : a1;
                w[c][3] = hi ? b1  : xs1;
            }
        }
        lsum += __shfl_xor(lsum, 32);
        l_run += lsum;

        // ---- PV (swapped): oacc[dblk] += mfma(Vt_frag, P_frag) -> C[d][q] ----
        #pragma unroll
        for (int c = 0; c < 4; ++c) {
            union { uint32_t u[4]; bf16x8 v; } pf;
            pf.u[0] = w[c][0]; pf.u[1] = w[c][1];
            pf.u[2] = w[c][2]; pf.u[3] = w[c][3];
            #pragma unroll
            for (int dblk = 0; dblk < 2; ++dblk) {
                const int vrow = dblk * 32 + l31;
                bf16x8 vf = *reinterpret_cast<const bf16x8*>(
                    &Vs[vrow * 64 + ((c * 16 + hi * 8) ^ swzr)]);
                oacc[dblk] = __builtin_amdgcn_mfma_f32_32x32x16_bf16(
                    vf, pf.v, oacc[dblk], 0, 0, 0);
            }
        }

        if (more) {
            __syncthreads();             // all waves done compute(t)
            #pragma unroll               // write tile t+1 into other buf
            for (int p = 0; p < 2; ++p) {
                const int row = strow + p * 32;
                const int sw  = row * 64 + (stslot ^ ((row & 7) << 3));
                *reinterpret_cast<bf16x8*>(&KV[cur ^ 1][sw])           = kreg[p];
                *reinterpret_cast<bf16x8*>(&KV[cur ^ 1][64 * 64 + sw]) = vreg[p];
            }
            __syncthreads();             // writes visible
            cur ^= 1;
        }
    }

    // ---- epilogue: out[b][q][h*64+d], d = (r&3)+8*(r>>2)+4*hi+32*dblk ----
    const float inv = 1.f / l_run;
    const int qg = q0 + wid * 32 + l31;
    float* obase = &out[((size_t)(b * S_LEN + qg)) * E_DIM + h * DHEAD];
    #pragma unroll
    for (int dblk = 0; dblk < 2; ++dblk) {
        #pragma unroll
        for (int g = 0; g < 4; ++g) {
            float4 f;
            f.x = oacc[dblk][g * 4 + 0] * inv;
            f.y = oacc[dblk][g * 4 + 1] * inv;
            f.z = oacc[dblk][g * 4 + 2] * inv;
            f.w = oacc[dblk][g * 4 + 3] * inv;
            *reinterpret_cast<float4*>(&obase[dblk * 32 + g * 8 + hi * 4]) = f;
        }
    }
}

// ---------------------------------------------------------------------------
extern "C" void kernel_launch(void* const* d_in, const int* in_sizes, int n_in,
                              void* d_out, int out_size, void* d_ws, size_t ws_size,
                              hipStream_t stream) {
    const float* x  = (const float*)d_in[0];
    const float* Wq = (const float*)d_in[1];
    const float* bq = (const float*)d_in[2];
    const float* Wk = (const float*)d_in[3];
    const float* bk = (const float*)d_in[4];
    const float* Wv = (const float*)d_in[5];
    const float* bv = (const float*)d_in[6];
    float* out = (float*)d_out;

    const size_t XN = (size_t)BATCH * S_LEN * E_DIM;   // 4M elems
    const size_t WN = (size_t)E_DIM * E_DIM;           // 1M elems
    ushort* xb  = (ushort*)d_ws;
    ushort* wqb = xb  + XN;
    ushort* wkb = wqb + WN;
    ushort* wvb = wkb + WN;
    ushort* qbb = wvb + WN;
    ushort* kbb = qbb + XN;
    ushort* vtb = kbb + XN;   // total ~38 MB

    convert_kernel<<<dim3(4096, 4), 256, 0, stream>>>(
        x, Wq, Wk, Wv, xb, wqb, wkb, wvb);

    qkv_mfma_kernel<<<dim3(32, 8, 3), 256, 0, stream>>>(
        xb, wqb, wkb, wvb, bq, bk, bv, qbb, kbb, vtb);

    attn_mfma32_kernel<<<dim3(512), 256, 0, stream>>>(qbb, kbb, vtb, out);
}